// Round 3
// baseline (98.160 us; speedup 1.0000x reference)
//
#include <hip/hip_runtime.h>

#define MAXS 512
#define SEG 4096            // points per segment (16 per thread)
#define CBLK 256            // 4 waves
#define CUT 12              // segments per batch that read speculatively
#define REC_U32 32          // padded status record: 128 B/segment
// record layout (u32): [0..7]=aggregate counts, [8..15]=inclusive (clamped
// at 512), [16]=flag (0 none, 1 agg ready, 2 inclusive ready)

__device__ __forceinline__ void publish8(unsigned* rec, int off,
                                         const unsigned v[8], unsigned flag) {
  #pragma unroll
  for (int o = 0; o < 8; ++o) rec[off + o] = v[o];
  __threadfence();  // device scope: counts visible before flag
  __hip_atomic_store(rec + 16, flag, __ATOMIC_RELEASE, __HIP_MEMORY_SCOPE_AGENT);
}

// Read this thread's 16 consecutive points; pack per-point (member<<3|oct)
// nibbles into mo; produce per-thread per-octant counts.
__device__ __forceinline__ void count_seg(const float* __restrict__ xp,
                                          const float* __restrict__ yp,
                                          const float* __restrict__ zp,
                                          int s0, int N, int tid,
                                          unsigned long long& mo, unsigned c[8]) {
  mo = 0ull;
  const int tb = s0 + tid * 16;
  #pragma unroll
  for (int jj = 0; jj < 4; ++jj) {
    const int g = tb + jj * 4;
    float xv[4], yv[4], zv[4];
    if (g + 4 <= N) {
      const float4 x4 = *(const float4*)(xp + g);
      const float4 y4 = *(const float4*)(yp + g);
      const float4 z4 = *(const float4*)(zp + g);
      xv[0] = x4.x; xv[1] = x4.y; xv[2] = x4.z; xv[3] = x4.w;
      yv[0] = y4.x; yv[1] = y4.y; yv[2] = y4.z; yv[3] = y4.w;
      zv[0] = z4.x; zv[1] = z4.y; zv[2] = z4.z; zv[3] = z4.w;
    } else {
      #pragma unroll
      for (int p = 0; p < 4; ++p) {  // sentinel 2.0f: never a member
        const bool v = (g + p) < N;
        xv[p] = v ? xp[g + p] : 2.0f;
        yv[p] = v ? yp[g + p] : 2.0f;
        zv[p] = v ? zp[g + p] : 2.0f;
      }
    }
    #pragma unroll
    for (int p = 0; p < 4; ++p) {
      // per-op IEEE rounding to match numpy (no FMA contraction at boundary)
      const float r2 = __fadd_rn(
          __fadd_rn(__fmul_rn(xv[p], xv[p]), __fmul_rn(yv[p], yv[p])),
          __fmul_rn(zv[p], zv[p]));
      const unsigned oct = ((xv[p] >= 0.f) ? 4u : 0u) |
                           ((yv[p] >= 0.f) ? 2u : 0u) |
                           ((zv[p] >= 0.f) ? 1u : 0u);
      const unsigned nib = ((r2 <= 1.0f) ? 8u : 0u) | oct;
      mo |= ((unsigned long long)nib) << (4 * (jj * 4 + p));
    }
  }
  #pragma unroll
  for (int o = 0; o < 8; ++o) c[o] = 0;
  #pragma unroll
  for (int p = 0; p < 16; ++p) {
    const unsigned nib = (unsigned)((mo >> (4 * p)) & 15ull);
    #pragma unroll
    for (int o = 0; o < 8; ++o) c[o] += (nib == (8u | (unsigned)o)) ? 1u : 0u;
  }
}

// Decoupled lookback over predecessor segments (wave 0 only; all predecessors
// fit in one wave since S<=64). Writes clamped base counts to sBase.
// Shortcut: ANY visible all-full inclusive record => prefix full (monotone).
__device__ __forceinline__ void lookback(const unsigned* __restrict__ recs,
                                         int s, int wid, int lane,
                                         unsigned sBase[8]) {
  if (wid != 0) return;
  const int t = s - 1 - lane;
  const bool valid = (t >= 0);
  const unsigned* rec = recs + (size_t)(valid ? t : 0) * REC_U32;
  int lstar;
  bool fullcut = false;
  for (;;) {
    const unsigned f = valid ? __hip_atomic_load(rec + 16, __ATOMIC_ACQUIRE,
                                                 __HIP_MEMORY_SCOPE_AGENT)
                             : 0u;
    bool myfull = false;
    if (valid && f == 2u) {
      unsigned mn = MAXS;
      #pragma unroll
      for (int o = 0; o < 8; ++o) {
        const unsigned v = __hip_atomic_load(rec + 8 + o, __ATOMIC_RELAXED,
                                             __HIP_MEMORY_SCOPE_AGENT);
        mn = v < mn ? v : mn;
      }
      myfull = (mn >= MAXS);
    }
    if (__ballot(myfull)) { fullcut = true; break; }
    const unsigned long long bi = __ballot(valid && f == 2u);
    if (bi) {
      const int ls = __ffsll(bi) - 1;  // nearest inclusive predecessor
      const unsigned long long need = (ls == 0) ? 0ull : ((1ull << ls) - 1ull);
      if ((__ballot(f >= 1u) & need) == need) { lstar = ls; break; }
    }
    __builtin_amdgcn_s_sleep(2);
  }
  unsigned vals[8];
  #pragma unroll
  for (int o = 0; o < 8; ++o) vals[o] = 0u;
  if (!fullcut) {
    if (lane < lstar) {           // aggregate contributor
      #pragma unroll
      for (int o = 0; o < 8; ++o)
        vals[o] = __hip_atomic_load(rec + o, __ATOMIC_RELAXED,
                                    __HIP_MEMORY_SCOPE_AGENT);
    } else if (lane == lstar) {   // inclusive anchor
      #pragma unroll
      for (int o = 0; o < 8; ++o)
        vals[o] = __hip_atomic_load(rec + 8 + o, __ATOMIC_RELAXED,
                                    __HIP_MEMORY_SCOPE_AGENT);
    }
  }
  #pragma unroll
  for (int o = 0; o < 8; ++o) {
    unsigned v = vals[o];
    #pragma unroll
    for (int d = 1; d < 64; d <<= 1) v += __shfl_xor(v, d, 64);
    if (lane == 0) sBase[o] = fullcut ? MAXS : (v > MAXS ? MAXS : v);
  }
}

__global__ __launch_bounds__(CBLK, 4) void octant_lookback_kernel(
    const float* __restrict__ pcs, int* __restrict__ out,
    unsigned* __restrict__ status, int N, int S) {
  const int bs = blockIdx.x;
  const int b = bs / S, s = bs - b * S;
  const int tid = threadIdx.x;
  const int wid = tid >> 6, lane = tid & 63;

  unsigned* rec = status + (size_t)bs * REC_U32;
  const unsigned* recs = status + (size_t)b * S * REC_U32;
  const float* __restrict__ xp = pcs + (size_t)b * 3 * N;
  const float* __restrict__ yp = xp + N;
  const float* __restrict__ zp = yp + N;
  int* __restrict__ ob = out + (size_t)b * 8 * MAXS;
  const int s0 = s * SEG;

  __shared__ unsigned sWtot[4][8];
  __shared__ unsigned sBase[8];

  if (s >= CUT) {  // lookback BEFORE touching point data
    lookback(recs, s, wid, lane, sBase);
    __syncthreads();
    bool full = true;
    #pragma unroll
    for (int o = 0; o < 8; ++o) full = full && (sBase[o] >= MAXS);
    if (full) {  // uniform: publish full inclusive, no data read at all
      if (tid == 0) {
        unsigned v[8];
        #pragma unroll
        for (int o = 0; o < 8; ++o) v[o] = MAXS;
        publish8(rec, 8, v, 2u);
      }
      return;
    }
  } else if (s == 0 && tid < 8) {
    sBase[tid] = 0;
  }

  // ---- read + count (speculative for s<CUT) ----
  unsigned long long mo;
  unsigned c[8], ex[8];
  count_seg(xp, yp, zp, s0, N, tid, mo, c);

  // block-wide scan: per-thread exclusive prefix + wave totals
  #pragma unroll
  for (int o = 0; o < 8; ++o) {
    unsigned v = c[o];
    #pragma unroll
    for (int d = 1; d < 64; d <<= 1) {
      const unsigned t = __shfl_up(v, (unsigned)d, 64);
      if (lane >= d) v += t;
    }
    ex[o] = v - c[o];
    if (lane == 63) sWtot[wid][o] = v;
  }
  __syncthreads();
  #pragma unroll
  for (int o = 0; o < 8; ++o) {
    #pragma unroll
    for (int w = 0; w < 4; ++w) ex[o] += (w < wid) ? sWtot[w][o] : 0u;
  }
  unsigned tot[8];
  #pragma unroll
  for (int o = 0; o < 8; ++o)
    tot[o] = sWtot[0][o] + sWtot[1][o] + sWtot[2][o] + sWtot[3][o];

  // ---- publish + obtain base ----
  if (s == 0) {
    if (tid == 0) {
      unsigned v[8];
      #pragma unroll
      for (int o = 0; o < 8; ++o) v[o] = tot[o] > MAXS ? MAXS : tot[o];
      publish8(rec, 8, v, 2u);
    }
  } else if (s < CUT) {
    if (tid == 0) publish8(rec, 0, tot, 1u);  // aggregate ASAP
    lookback(recs, s, wid, lane, sBase);
    __syncthreads();
    if (tid == 0) {
      unsigned v[8];
      #pragma unroll
      for (int o = 0; o < 8; ++o) {
        const unsigned iv = sBase[o] + tot[o];
        v[o] = iv > MAXS ? MAXS : iv;
      }
      publish8(rec, 8, v, 2u);
    }
  } else {  // working tail block: base already in sBase
    if (tid == 0) {
      unsigned v[8];
      #pragma unroll
      for (int o = 0; o < 8; ++o) {
        const unsigned iv = sBase[o] + tot[o];
        v[o] = iv > MAXS ? MAXS : iv;
      }
      publish8(rec, 8, v, 2u);
    }
  }
  __syncthreads();  // sBase valid for all (s==0 zeros / lookback result)

  // ---- ordered scatter write from packed nibbles ----
  unsigned b8[8];
  #pragma unroll
  for (int o = 0; o < 8; ++o) b8[o] = sBase[o];
  const unsigned gbase = (unsigned)(s0 + tid * 16);
  #pragma unroll
  for (int o = 0; o < 8; ++o) {
    unsigned r = b8[o] + ex[o];
    #pragma unroll
    for (int p = 0; p < 16; ++p) {
      const unsigned nib = (unsigned)((mo >> (4 * p)) & 15ull);
      if (nib == (8u | (unsigned)o)) {
        if (r < MAXS) ob[o * MAXS + r] = (int)(gbase + p);
        ++r;
      }
    }
  }

  // ---- last segment fills unfilled slots with -1 (no-op when all full) ----
  if (s == S - 1) {
    for (int i = tid; i < 8 * MAXS; i += CBLK) {
      const int o = i >> 9, rr = i & (MAXS - 1);
      const unsigned incl_o = sBase[o] + sWtot[0][o] + sWtot[1][o] +
                              sWtot[2][o] + sWtot[3][o];
      if ((unsigned)rr >= (incl_o > MAXS ? MAXS : incl_o)) ob[i] = -1;
    }
  }
}

extern "C" void kernel_launch(void* const* d_in, const int* in_sizes, int n_in,
                              void* d_out, int out_size, void* d_ws, size_t ws_size,
                              hipStream_t stream) {
  const float* pcs = (const float*)d_in[0];
  int* out = (int*)d_out;
  const int B = out_size / (8 * MAXS);   // 16
  const int N = in_sizes[0] / (3 * B);   // 200000
  const int S = (N + SEG - 1) / SEG;     // 49 (must be <= 64 for 1-wave lookback)

  unsigned* status = (unsigned*)d_ws;
  hipMemsetAsync(status, 0, (size_t)B * S * REC_U32 * sizeof(unsigned), stream);
  octant_lookback_kernel<<<B * S, CBLK, 0, stream>>>(pcs, out, status, N, S);
}

// Round 4
// 91.963 us; speedup vs baseline: 1.0674x; 1.0674x over previous
//
#include <hip/hip_runtime.h>

#define MAXS 512
#define SEG 4096      // points per segment (16 per thread)
#define CBLK 256      // 4 waves

// Fused single-kernel octant query.
// All B*S blocks are co-resident (784 blocks <= 4/CU * 256 CU guaranteed by
// __launch_bounds__(256,4) => <=128 VGPR), so a single-hop per-batch arrival
// counter is deadlock-free: every block publishes BEFORE it waits, and waits
// only on the counter (no chained lookback — that was R3's 98us failure).
__global__ __launch_bounds__(CBLK, 4) void octant_fused_kernel(
    const float* __restrict__ pcs, int* __restrict__ out,
    unsigned* __restrict__ done, unsigned* __restrict__ counts,
    int N, int S) {
  const int bs = blockIdx.x;
  const int b = bs / S, s = bs - b * S;
  const int tid = threadIdx.x;
  const int wid = tid >> 6, lane = tid & 63;

  const float* __restrict__ xp = pcs + (size_t)b * 3 * N;
  const float* __restrict__ yp = xp + N;
  const float* __restrict__ zp = yp + N;
  int* __restrict__ ob = out + (size_t)b * 8 * MAXS;
  const int s0 = s * SEG;

  __shared__ unsigned sW[4][8];    // per-wave per-octant totals (kept intact)
  __shared__ unsigned sBase[8];    // prefix base for this segment

  // ---- 1. read own segment once; pack (member<<3 | oct) nibbles ----
  unsigned long long mo = 0ull;
  const int tb = s0 + tid * 16;
  #pragma unroll
  for (int jj = 0; jj < 4; ++jj) {
    const int g = tb + jj * 4;
    float xv[4], yv[4], zv[4];
    if (g + 4 <= N) {
      const float4 x4 = *(const float4*)(xp + g);
      const float4 y4 = *(const float4*)(yp + g);
      const float4 z4 = *(const float4*)(zp + g);
      xv[0] = x4.x; xv[1] = x4.y; xv[2] = x4.z; xv[3] = x4.w;
      yv[0] = y4.x; yv[1] = y4.y; yv[2] = y4.z; yv[3] = y4.w;
      zv[0] = z4.x; zv[1] = z4.y; zv[2] = z4.z; zv[3] = z4.w;
    } else {
      #pragma unroll
      for (int p = 0; p < 4; ++p) {  // sentinel 2.0f: never a member
        const bool v = (g + p) < N;
        xv[p] = v ? xp[g + p] : 2.0f;
        yv[p] = v ? yp[g + p] : 2.0f;
        zv[p] = v ? zp[g + p] : 2.0f;
      }
    }
    #pragma unroll
    for (int p = 0; p < 4; ++p) {
      // per-op IEEE f32 rounding matches numpy (no FMA at the r2~1 boundary)
      const float r2 = __fadd_rn(
          __fadd_rn(__fmul_rn(xv[p], xv[p]), __fmul_rn(yv[p], yv[p])),
          __fmul_rn(zv[p], zv[p]));
      const unsigned oct = ((xv[p] >= 0.f) ? 4u : 0u) |
                           ((yv[p] >= 0.f) ? 2u : 0u) |
                           ((zv[p] >= 0.f) ? 1u : 0u);
      const unsigned nib = ((r2 <= 1.0f) ? 8u : 0u) | oct;
      mo |= ((unsigned long long)nib) << (4 * (jj * 4 + p));
    }
  }
  unsigned c[8];
  #pragma unroll
  for (int o = 0; o < 8; ++o) c[o] = 0;
  #pragma unroll
  for (int p = 0; p < 16; ++p) {
    const unsigned nib = (unsigned)((mo >> (4 * p)) & 15ull);
    #pragma unroll
    for (int o = 0; o < 8; ++o) c[o] += (nib == (8u | (unsigned)o)) ? 1u : 0u;
  }

  // ---- 2. wave-level exclusive scan; lane63 carries the wave total ----
  unsigned ex[8];
  #pragma unroll
  for (int o = 0; o < 8; ++o) {
    unsigned v = c[o];
    #pragma unroll
    for (int d = 1; d < 64; d <<= 1) {
      const unsigned t = __shfl_up(v, (unsigned)d, 64);
      if (lane >= d) v += t;
    }
    ex[o] = v - c[o];
    if (lane == 63) sW[wid][o] = v;
  }
  __syncthreads();

  // ---- 3. publish block totals; one release hop on the batch counter ----
  if (tid < 8)
    counts[(size_t)bs * 8 + tid] = sW[0][tid] + sW[1][tid] + sW[2][tid] + sW[3][tid];
  __syncthreads();
  if (tid == 0) {
    __threadfence();  // counts visible device-wide before arrival
    __hip_atomic_fetch_add(done + b, 1u, __ATOMIC_RELEASE,
                           __HIP_MEMORY_SCOPE_AGENT);
    if (s > 0) {
      while (__hip_atomic_load(done + b, __ATOMIC_ACQUIRE,
                               __HIP_MEMORY_SCOPE_AGENT) < (unsigned)S)
        __builtin_amdgcn_s_sleep(8);
    }
  }
  __syncthreads();

  // ---- 4. prefix base over predecessors (wave 0; S<=64) ----
  if (wid == 0) {
    unsigned v0 = 0, v1 = 0, v2 = 0, v3 = 0, v4 = 0, v5 = 0, v6 = 0, v7 = 0;
    if (lane < s) {
      const unsigned* cr = counts + (size_t)(b * S + lane) * 8;
      // relaxed agent-scope loads bypass L1 => guaranteed fresh from L2
      v0 = __hip_atomic_load(cr + 0, __ATOMIC_RELAXED, __HIP_MEMORY_SCOPE_AGENT);
      v1 = __hip_atomic_load(cr + 1, __ATOMIC_RELAXED, __HIP_MEMORY_SCOPE_AGENT);
      v2 = __hip_atomic_load(cr + 2, __ATOMIC_RELAXED, __HIP_MEMORY_SCOPE_AGENT);
      v3 = __hip_atomic_load(cr + 3, __ATOMIC_RELAXED, __HIP_MEMORY_SCOPE_AGENT);
      v4 = __hip_atomic_load(cr + 4, __ATOMIC_RELAXED, __HIP_MEMORY_SCOPE_AGENT);
      v5 = __hip_atomic_load(cr + 5, __ATOMIC_RELAXED, __HIP_MEMORY_SCOPE_AGENT);
      v6 = __hip_atomic_load(cr + 6, __ATOMIC_RELAXED, __HIP_MEMORY_SCOPE_AGENT);
      v7 = __hip_atomic_load(cr + 7, __ATOMIC_RELAXED, __HIP_MEMORY_SCOPE_AGENT);
    }
    #pragma unroll
    for (int d = 1; d < 64; d <<= 1) {
      v0 += __shfl_xor(v0, d, 64); v1 += __shfl_xor(v1, d, 64);
      v2 += __shfl_xor(v2, d, 64); v3 += __shfl_xor(v3, d, 64);
      v4 += __shfl_xor(v4, d, 64); v5 += __shfl_xor(v5, d, 64);
      v6 += __shfl_xor(v6, d, 64); v7 += __shfl_xor(v7, d, 64);
    }
    if (lane == 0) {
      sBase[0] = v0; sBase[1] = v1; sBase[2] = v2; sBase[3] = v3;
      sBase[4] = v4; sBase[5] = v5; sBase[6] = v6; sBase[7] = v7;
    }
  }
  __syncthreads();

  // ---- 5. early exit (block-uniform): this segment contributes nothing ----
  if (sBase[0] >= MAXS && sBase[1] >= MAXS && sBase[2] >= MAXS &&
      sBase[3] >= MAXS && sBase[4] >= MAXS && sBase[5] >= MAXS &&
      sBase[6] >= MAXS && sBase[7] >= MAXS)
    return;

  // ---- 6. cross-wave prefix (sW still intact) + register scatter-write ----
  #pragma unroll
  for (int o = 0; o < 8; ++o) {
    #pragma unroll
    for (int w = 0; w < 4; ++w) ex[o] += (w < wid) ? sW[w][o] : 0u;
  }
  #pragma unroll
  for (int o = 0; o < 8; ++o) {
    unsigned r = sBase[o] + ex[o];
    #pragma unroll
    for (int p = 0; p < 16; ++p) {
      const unsigned nib = (unsigned)((mo >> (4 * p)) & 15ull);
      if (nib == (8u | (unsigned)o)) {
        if (r < MAXS) ob[o * MAXS + (int)r] = tb + p;
        ++r;
      }
    }
  }
  // unfilled slots stay -1 from the 0xFF memset
}

extern "C" void kernel_launch(void* const* d_in, const int* in_sizes, int n_in,
                              void* d_out, int out_size, void* d_ws, size_t ws_size,
                              hipStream_t stream) {
  const float* pcs = (const float*)d_in[0];
  int* out = (int*)d_out;
  const int B = out_size / (8 * MAXS);   // 16
  const int N = in_sizes[0] / (3 * B);   // 200000
  const int S = (N + SEG - 1) / SEG;     // 49 (<= 64 for 1-wave prefix)

  unsigned* done = (unsigned*)d_ws;                 // B u32
  unsigned* counts = done + B;                      // B*S*8 u32

  hipMemsetAsync(done, 0, (size_t)(B + B * S * 8) * sizeof(unsigned), stream);
  hipMemsetAsync(out, 0xFF, (size_t)out_size * sizeof(int), stream);
  octant_fused_kernel<<<B * S, CBLK, 0, stream>>>(pcs, out, done, counts, N, S);
}

// Round 5
// 24.647 us; speedup vs baseline: 3.9826x; 3.7312x over previous
//
#include <hip/hip_runtime.h>

#define MAXS 512
#define SEG 4096         // points per segment
#define K1BLK 1024       // classify: 1 float4 (4 points) per thread
#define K2BLK 256        // write: 16 points per thread

// ---------------------------------------------------------------------------
// Pass 1: classify every point once (full 38.4 MB read — unavoidable for
// exact counts), emit per-(batch,segment) octant counts and per-point packed
// nibbles (member<<3 | oct) so pass 2 never re-reads pcs.
// ---------------------------------------------------------------------------
__global__ __launch_bounds__(K1BLK) void classify_kernel(
    const float* __restrict__ pcs, unsigned short* __restrict__ nibs,
    unsigned* __restrict__ counts, int N, int S) {
  const int bs = blockIdx.x;
  const int b = bs / S, s = bs - b * S;
  const int tid = threadIdx.x, wid = tid >> 6;
  const float* __restrict__ xp = pcs + (size_t)b * 3 * N;
  const float* __restrict__ yp = xp + N;
  const float* __restrict__ zp = yp + N;
  const int g = s * SEG + tid * 4;

  float xv[4], yv[4], zv[4];
  if (g + 4 <= N) {  // N%4==0 -> a thread is fully in or fully out
    const float4 x4 = *(const float4*)(xp + g);
    const float4 y4 = *(const float4*)(yp + g);
    const float4 z4 = *(const float4*)(zp + g);
    xv[0] = x4.x; xv[1] = x4.y; xv[2] = x4.z; xv[3] = x4.w;
    yv[0] = y4.x; yv[1] = y4.y; yv[2] = y4.z; yv[3] = y4.w;
    zv[0] = z4.x; zv[1] = z4.y; zv[2] = z4.z; zv[3] = z4.w;
  } else {
    #pragma unroll
    for (int p = 0; p < 4; ++p) { xv[p] = 2.0f; yv[p] = 2.0f; zv[p] = 2.0f; }
  }

  unsigned mo16 = 0;
  unsigned long long clo = 0ull, chi = 0ull;  // u16 fields: oct 0..3 / 4..7
  #pragma unroll
  for (int p = 0; p < 4; ++p) {
    // per-op IEEE f32 rounding matches numpy (no FMA at the r2~1 boundary)
    const float r2 = __fadd_rn(
        __fadd_rn(__fmul_rn(xv[p], xv[p]), __fmul_rn(yv[p], yv[p])),
        __fmul_rn(zv[p], zv[p]));
    const bool member = (r2 <= 1.0f);
    const unsigned oct = ((xv[p] >= 0.f) ? 4u : 0u) |
                         ((yv[p] >= 0.f) ? 2u : 0u) |
                         ((zv[p] >= 0.f) ? 1u : 0u);
    mo16 |= (((member ? 8u : 0u) | oct) << (4 * p));
    const unsigned long long inc = 1ull << ((oct & 3u) * 16u);
    clo += (member && oct < 4u) ? inc : 0ull;
    chi += (member && oct >= 4u) ? inc : 0ull;
  }

  // wave butterfly reduce (packed fields; wave max 64*4=256 < 65536)
  #pragma unroll
  for (int d = 1; d < 64; d <<= 1) {
    clo += __shfl_xor(clo, d, 64);
    chi += __shfl_xor(chi, d, 64);
  }
  __shared__ unsigned long long sW[K1BLK / 64][2];
  if ((tid & 63) == 0) { sW[wid][0] = clo; sW[wid][1] = chi; }
  __syncthreads();
  if (tid < 8) {
    unsigned t = 0;
    #pragma unroll
    for (int w = 0; w < K1BLK / 64; ++w) {
      const unsigned long long v = sW[w][tid >> 2];
      t += (unsigned)((v >> ((tid & 3) * 16)) & 0xffffull);
    }
    counts[(size_t)bs * 8 + tid] = t;
  }
  nibs[(size_t)bs * K1BLK + tid] = (unsigned short)mo16;
}

// ---------------------------------------------------------------------------
// Pass 2: per segment, prefix base from counts (L2/L3-hit); most blocks exit
// immediately (all octants already full). Last segment's block back-fills -1
// tails. Survivors rebuild stable ranks from nibbles and scatter.
// ---------------------------------------------------------------------------
__global__ __launch_bounds__(K2BLK) void write_kernel(
    const unsigned short* __restrict__ nibs, const unsigned* __restrict__ counts,
    int* __restrict__ out, int N, int S) {
  const int bs = blockIdx.x;
  const int b = bs / S, s = bs - b * S;
  const int tid = threadIdx.x, wid = tid >> 6, lane = tid & 63;
  int* __restrict__ ob = out + (size_t)b * 8 * MAXS;

  __shared__ unsigned sBase[8], sTot[8];
  __shared__ unsigned long long sW[K2BLK / 64][2];

  if (wid == 0) {
    unsigned v[8], bse[8];
    #pragma unroll
    for (int o = 0; o < 8; ++o) v[o] = 0u;
    if (lane < S) {
      const unsigned* cr = counts + (size_t)(b * S + lane) * 8;
      const uint4 a = *(const uint4*)cr;
      const uint4 c2 = *(const uint4*)(cr + 4);
      v[0] = a.x; v[1] = a.y; v[2] = a.z; v[3] = a.w;
      v[4] = c2.x; v[5] = c2.y; v[6] = c2.z; v[7] = c2.w;
    }
    #pragma unroll
    for (int o = 0; o < 8; ++o) bse[o] = (lane < s) ? v[o] : 0u;
    #pragma unroll
    for (int d = 1; d < 64; d <<= 1) {
      #pragma unroll
      for (int o = 0; o < 8; ++o) {
        v[o] += __shfl_xor(v[o], d, 64);
        bse[o] += __shfl_xor(bse[o], d, 64);
      }
    }
    if (lane == 0) {
      #pragma unroll
      for (int o = 0; o < 8; ++o) { sBase[o] = bse[o]; sTot[o] = v[o]; }
    }
  }
  __syncthreads();

  const bool all_full =
      sBase[0] >= MAXS && sBase[1] >= MAXS && sBase[2] >= MAXS &&
      sBase[3] >= MAXS && sBase[4] >= MAXS && sBase[5] >= MAXS &&
      sBase[6] >= MAXS && sBase[7] >= MAXS;

  if (s == S - 1) {  // back-fill -1 tails from grand totals (replaces memset)
    for (int i = tid; i < 8 * MAXS; i += K2BLK) {
      const int o = i >> 9;
      const unsigned rr = (unsigned)(i & (MAXS - 1));
      const unsigned lim = sTot[o] > MAXS ? MAXS : sTot[o];
      if (rr >= lim) ob[i] = -1;
    }
  }
  if (all_full) return;  // block-uniform: segment contributes nothing

  // rebuild stable ranks from this segment's nibble record (2 KB, L2/L3-hit)
  const unsigned long long w4 =
      *(const unsigned long long*)(nibs + (size_t)bs * K1BLK + tid * 4);
  unsigned long long clo = 0ull, chi = 0ull;
  #pragma unroll
  for (int p = 0; p < 16; ++p) {
    const unsigned nib = (unsigned)((w4 >> (4 * p)) & 15ull);
    const bool member = (nib & 8u) != 0u;
    const unsigned oct = nib & 7u;
    const unsigned long long inc = 1ull << ((oct & 3u) * 16u);
    clo += (member && oct < 4u) ? inc : 0ull;
    chi += (member && oct >= 4u) ? inc : 0ull;
  }
  // wave inclusive scan (fields <= 64*16=1024 < 65536)
  unsigned long long ilo = clo, ihi = chi;
  #pragma unroll
  for (int d = 1; d < 64; d <<= 1) {
    const unsigned long long tl = __shfl_up(ilo, (unsigned)d, 64);
    const unsigned long long th = __shfl_up(ihi, (unsigned)d, 64);
    if (lane >= d) { ilo += tl; ihi += th; }
  }
  unsigned long long elo = ilo - clo, ehi = ihi - chi;
  if (lane == 63) { sW[wid][0] = ilo; sW[wid][1] = ihi; }
  __syncthreads();
  #pragma unroll
  for (int w = 0; w < K2BLK / 64; ++w) {
    if (w < wid) { elo += sW[w][0]; ehi += sW[w][1]; }
  }

  const int pbase = s * SEG + tid * 16;
  #pragma unroll
  for (int o = 0; o < 8; ++o) {
    const unsigned long long ef = (o < 4) ? elo : ehi;
    unsigned r = sBase[o] + (unsigned)((ef >> ((o & 3) * 16)) & 0xffffull);
    #pragma unroll
    for (int p = 0; p < 16; ++p) {
      const unsigned nib = (unsigned)((w4 >> (4 * p)) & 15ull);
      if (nib == (8u | (unsigned)o)) {
        if (r < MAXS) ob[o * MAXS + (int)r] = pbase + p;
        ++r;
      }
    }
  }
}

extern "C" void kernel_launch(void* const* d_in, const int* in_sizes, int n_in,
                              void* d_out, int out_size, void* d_ws, size_t ws_size,
                              hipStream_t stream) {
  const float* pcs = (const float*)d_in[0];
  int* out = (int*)d_out;
  const int B = out_size / (8 * MAXS);   // 16
  const int N = in_sizes[0] / (3 * B);   // 200000
  const int S = (N + SEG - 1) / SEG;     // 49 (<= 64 for 1-wave prefix)

  unsigned* counts = (unsigned*)d_ws;                       // B*S*8 u32
  unsigned short* nibs = (unsigned short*)(counts + (size_t)B * S * 8);

  classify_kernel<<<B * S, K1BLK, 0, stream>>>(pcs, nibs, counts, N, S);
  write_kernel<<<B * S, K2BLK, 0, stream>>>(nibs, counts, out, N, S);
}